// Round 1
// baseline (157.941 us; speedup 1.0000x reference)
//
#include <hip/hip_runtime.h>
#include <hip/hip_bf16.h>

// NoSharedRnnAgent: per-agent fc1+ReLU -> GRU cell -> fc2, batched over 32 agents.
// All inputs fp32; compute via bf16 MFMA (harness threshold = 2% of max|ref|).
//
// d_in: 0=inputs[8192,512] 1=hidden[8192,512] 2=W1[32,512,512] 3=b1[32,512]
//       4=W_ih[32,1536,512] 5=b_ih[32,1536] 6=W_hh[32,1536,512] 7=b_hh[32,1536]
//       8=W2[32,64,512] 9=b2[32,64]
// d_out: q[8192,64] fp32, then h[8192,512] fp32.
// Row mapping everywhere: global row = b*32 + a  (A=32 agents in the middle dim).

typedef __attribute__((ext_vector_type(8))) __bf16 bf16x8;
typedef __attribute__((ext_vector_type(4))) float  f32x4;

constexpr int NAGENT = 32;
constexpr int KC     = 512;   // K of every GEMM in this net
constexpr int MROWS  = 256;   // batch rows per agent
constexpr int NKT    = KC / 32;

// C[M,N] = act(A[M,K] @ W[N,K]^T + bias), batched per agent.
// A element (b,k) at Ap[((b0+b)*32 + a)*512 + k]  (fp32 or bf16 per ABF16).
// W element (n,k) at Wp[a*N*512 + n*512 + k] (fp32, converted to bf16 in staging).
// LDS layout: [buf][kslice(0..3)][row][8 bf16] -> conflict-free ds_read_b128/write.
template <int BM, int BN, int WM, int WN, bool ABF16, int ACT, bool OBF16>
__global__ __launch_bounds__(WM * WN * 64) void gemm_bt(
    const void* __restrict__ Ap, const float* __restrict__ Wp,
    const float* __restrict__ bp, void* __restrict__ Op, const int N) {
  constexpr int NTHR = WM * WN * 64;
  constexpr int FM = BM / (16 * WM);
  constexpr int FN = BN / (16 * WN);
  constexpr int CA = (BM * 4) / NTHR;  // staging chunks (8 elems each) per thread
  constexpr int CB = (BN * 4) / NTHR;
  static_assert(CA * NTHR == BM * 4 && CB * NTHR == BN * 4, "staging divisibility");

  __shared__ __attribute__((aligned(16))) __bf16 lA[2][4][BM][8];
  __shared__ __attribute__((aligned(16))) __bf16 lB[2][4][BN][8];

  const int tid = threadIdx.x;
  const int NT = N / BN;
  const int MT = MROWS / BM;
  const int tilesPer = MT * NT;
  const int a  = blockIdx.x / tilesPer;
  const int rm = blockIdx.x % tilesPer;
  const int b0 = (rm / NT) * BM;
  const int n0 = (rm % NT) * BN;

  const int wave = tid >> 6;
  const int lane = tid & 63;
  const int wm = wave / WN, wn = wave % WN;
  const int lr = lane & 15, lk = lane >> 4;

  const float*  Af = (const float*)Ap;
  const __bf16* Ab = (const __bf16*)Ap;
  const float*  Wb = Wp + (size_t)a * N * KC + (size_t)n0 * KC;

  int ar[CA], aks[CA];
  size_t aoff[CA];
#pragma unroll
  for (int c = 0; c < CA; ++c) {
    const int idx = tid + c * NTHR;
    ar[c] = idx >> 2;
    aks[c] = idx & 3;
    aoff[c] = ((size_t)(b0 + ar[c]) * NAGENT + a) * KC + aks[c] * 8;
  }
  int br[CB], bks[CB];
  size_t boff[CB];
#pragma unroll
  for (int c = 0; c < CB; ++c) {
    const int idx = tid + c * NTHR;
    br[c] = idx >> 2;
    bks[c] = idx & 3;
    boff[c] = (size_t)br[c] * KC + bks[c] * 8;
  }

  bf16x8 sA[CA], sB[CB];

  auto cvt8 = [](const float* p) {
    f32x4 u = *(const f32x4*)p;
    f32x4 v = *(const f32x4*)(p + 4);
    bf16x8 w;
    w[0] = (__bf16)u[0]; w[1] = (__bf16)u[1]; w[2] = (__bf16)u[2]; w[3] = (__bf16)u[3];
    w[4] = (__bf16)v[0]; w[5] = (__bf16)v[1]; w[6] = (__bf16)v[2]; w[7] = (__bf16)v[3];
    return w;
  };

  auto loadT = [&](int t) {
#pragma unroll
    for (int c = 0; c < CA; ++c) {
      if constexpr (ABF16) {
        sA[c] = *(const bf16x8*)(Ab + aoff[c] + t * 32);
      } else {
        sA[c] = cvt8(Af + aoff[c] + t * 32);
      }
    }
#pragma unroll
    for (int c = 0; c < CB; ++c) sB[c] = cvt8(Wb + boff[c] + t * 32);
  };

  auto writeT = [&](int buf) {
#pragma unroll
    for (int c = 0; c < CA; ++c) *(bf16x8*)(&lA[buf][aks[c]][ar[c]][0]) = sA[c];
#pragma unroll
    for (int c = 0; c < CB; ++c) *(bf16x8*)(&lB[buf][bks[c]][br[c]][0]) = sB[c];
  };

  f32x4 acc[FM][FN];
#pragma unroll
  for (int i = 0; i < FM; ++i)
#pragma unroll
    for (int j = 0; j < FN; ++j) acc[i][j] = {0.f, 0.f, 0.f, 0.f};

  auto computeT = [&](int buf) {
    bf16x8 af[FM], bv[FN];
#pragma unroll
    for (int i = 0; i < FM; ++i)
      af[i] = *(const bf16x8*)(&lA[buf][lk][wm * FM * 16 + i * 16 + lr][0]);
#pragma unroll
    for (int j = 0; j < FN; ++j)
      bv[j] = *(const bf16x8*)(&lB[buf][lk][wn * FN * 16 + j * 16 + lr][0]);
#pragma unroll
    for (int i = 0; i < FM; ++i)
#pragma unroll
      for (int j = 0; j < FN; ++j)
        acc[i][j] = __builtin_amdgcn_mfma_f32_16x16x32_bf16(af[i], bv[j], acc[i][j], 0, 0, 0);
  };

  loadT(0);
  writeT(0);
  int cur = 0;
  for (int t = 0; t < NKT; ++t) {
    __syncthreads();
    if (t + 1 < NKT) loadT(t + 1);  // HBM latency hides under MFMA below
    computeT(cur);
    if (t + 1 < NKT) {
      writeT(cur ^ 1);  // other buffer: no race with waves still reading cur
      cur ^= 1;
    }
  }

  // epilogue: bias + activation + store (C/D map: col=lane&15, row=(lane>>4)*4+e)
#pragma unroll
  for (int j = 0; j < FN; ++j) {
    const int col = n0 + wn * FN * 16 + j * 16 + lr;
    const float bv = bp[(size_t)a * N + col];
#pragma unroll
    for (int i = 0; i < FM; ++i) {
      const int row0 = b0 + wm * FM * 16 + i * 16 + lk * 4;
#pragma unroll
      for (int e = 0; e < 4; ++e) {
        float v = acc[i][j][e] + bv;
        if (ACT == 1) v = fmaxf(v, 0.f);
        const size_t o = ((size_t)(row0 + e) * NAGENT + a) * N + col;
        if constexpr (OBF16)
          ((__bf16*)Op)[o] = (__bf16)v;
        else
          ((float*)Op)[o] = v;
      }
    }
  }
}

__device__ __forceinline__ float sigmoid_f(float x) {
  return 1.f / (1.f + __expf(-x));
}
__device__ __forceinline__ float tanh_f(float x) {
  float xc = fminf(fmaxf(x, -15.f), 15.f);
  float a = __expf(2.f * xc);
  return (a - 1.f) / (a + 1.f);
}

// gates: r=sig(gx_r+gh_r), z=sig(gx_z+gh_z), n=tanh(gx_n + r*gh_n),
//        h=(1-z)*n + z*h_in. Writes h fp32 (d_out) and bf16 (ws for fc2).
__global__ __launch_bounds__(256) void gates_k(
    const __bf16* __restrict__ gx, const __bf16* __restrict__ gh,
    const float* __restrict__ hin, float* __restrict__ hout,
    __bf16* __restrict__ hbf) {
  const size_t i8 = (size_t)blockIdx.x * 256 + threadIdx.x;
  const size_t base = i8 * 8;          // element index into [8192*512)
  const size_t row = base >> 9;        // global row (b*32+a)
  const int g = (int)(base & 511);
  const size_t gb = row * 1536 + g;

  bf16x8 xr = *(const bf16x8*)(gx + gb);
  bf16x8 xz = *(const bf16x8*)(gx + gb + 512);
  bf16x8 xn = *(const bf16x8*)(gx + gb + 1024);
  bf16x8 hr = *(const bf16x8*)(gh + gb);
  bf16x8 hz = *(const bf16x8*)(gh + gb + 512);
  bf16x8 hn = *(const bf16x8*)(gh + gb + 1024);
  f32x4 h0 = *(const f32x4*)(hin + base);
  f32x4 h1 = *(const f32x4*)(hin + base + 4);

  f32x4 o0, o1;
  bf16x8 ob;
#pragma unroll
  for (int e = 0; e < 8; ++e) {
    const float hprev = (e < 4) ? h0[e] : h1[e - 4];
    const float r = sigmoid_f((float)xr[e] + (float)hr[e]);
    const float z = sigmoid_f((float)xz[e] + (float)hz[e]);
    const float n = tanh_f((float)xn[e] + r * (float)hn[e]);
    const float h = (1.f - z) * n + z * hprev;
    if (e < 4) o0[e] = h; else o1[e - 4] = h;
    ob[e] = (__bf16)h;
  }
  *(f32x4*)(hout + base) = o0;
  *(f32x4*)(hout + base + 4) = o1;
  *(bf16x8*)(hbf + base) = ob;
}

extern "C" void kernel_launch(void* const* d_in, const int* in_sizes, int n_in,
                              void* d_out, int out_size, void* d_ws, size_t ws_size,
                              hipStream_t stream) {
  const float* inputs = (const float*)d_in[0];
  const float* hidden = (const float*)d_in[1];
  const float* W1   = (const float*)d_in[2];
  const float* b1   = (const float*)d_in[3];
  const float* W_ih = (const float*)d_in[4];
  const float* b_ih = (const float*)d_in[5];
  const float* W_hh = (const float*)d_in[6];
  const float* b_hh = (const float*)d_in[7];
  const float* W2   = (const float*)d_in[8];
  const float* b2   = (const float*)d_in[9];

  float* out_q = (float*)d_out;
  float* out_h = out_q + (size_t)8192 * 64;

  char* ws = (char*)d_ws;
  __bf16* x1  = (__bf16*)(ws);                       //  8 MiB [8192,512]
  __bf16* gx  = (__bf16*)(ws + ((size_t)8  << 20));  // 24 MiB [8192,1536]
  __bf16* gh  = (__bf16*)(ws + ((size_t)32 << 20));  // 24 MiB [8192,1536]
  __bf16* hbf = (__bf16*)(ws + ((size_t)56 << 20));  //  8 MiB [8192,512]

  // fc1: x1 = relu(inputs @ W1^T + b1)   [per agent 256x512x512]
  gemm_bt<128, 128, 2, 2, false, 1, true>
      <<<32 * 2 * 4, 256, 0, stream>>>(inputs, W1, b1, x1, 512);
  // gx = x1 @ W_ih^T + b_ih              [256x1536x512]
  gemm_bt<128, 128, 2, 2, true, 0, true>
      <<<32 * 2 * 12, 256, 0, stream>>>(x1, W_ih, b_ih, gx, 1536);
  // gh = hidden @ W_hh^T + b_hh          [256x1536x512]
  gemm_bt<128, 128, 2, 2, false, 0, true>
      <<<32 * 2 * 12, 256, 0, stream>>>(hidden, W_hh, b_hh, gh, 1536);
  // gates -> h (fp32 to d_out, bf16 to ws)
  gates_k<<<(8192 * 512 / 8) / 256, 256, 0, stream>>>(gx, gh, hidden, out_h, hbf);
  // fc2: q = h @ W2^T + b2               [256x64x512]
  gemm_bt<64, 64, 2, 2, true, 0, false>
      <<<32 * 4 * 1, 256, 0, stream>>>(hbf, W2, b2, out_q, 64);
}